// Round 4
// baseline (466.441 us; speedup 1.0000x reference)
//
#include <hip/hip_runtime.h>
#include <hip/hip_bf16.h>
#include <math.h>

#define BE   256
#define DIM  256
#define OUTD 128
#define LCL  256
#define LEV  512
#define NEGV -1e18f

typedef short  bf16x8  __attribute__((ext_vector_type(8)));
typedef float  floatx4 __attribute__((ext_vector_type(4)));

union BF1 { __hip_bfloat16 h; unsigned short u; };
union BF2 { __hip_bfloat162 h; unsigned int u; };

__device__ __forceinline__ float fast_tanh(float x) {
    float xc = fminf(fmaxf(x, -15.f), 15.f);
    float e = __expf(2.f * xc);
    return (e - 1.f) * __builtin_amdgcn_rcpf(e + 1.f);
}

// ---------------------------------------------------------------------------
// K1: blocks [0,1024): claim-mean partials, float4-vectorized.
//     pair = b>>2, chunk = b&3 (64 rows each). partial[b][256].
// blocks [1024,1280): W[:D] fp32 -> bf16 W^T (128 x 256).
// ---------------------------------------------------------------------------
__global__ __launch_bounds__(256) void k_prep(
    const float* __restrict__ claim,
    const float* __restrict__ W1, const float* __restrict__ W2,
    float* __restrict__ cpart,
    unsigned short* __restrict__ WT1, unsigned short* __restrict__ WT2)
{
    const int b = blockIdx.x;
    const int t = threadIdx.x;
    if (b >= 1024) {
        const int idx = b - 1024;           // 0..255
        const int side = idx >> 7;
        const int n = idx & 127;
        const float* W = side ? W2 : W1;
        unsigned short* WT = side ? WT2 : WT1;
        BF1 c; c.h = __float2bfloat16(W[(size_t)t * OUTD + n]);
        WT[n * DIM + t] = c.u;
        return;
    }
    __shared__ float4 red[4][64];
    const int d4 = t & 63, rg = t >> 6;
    const float4* sp4 = (const float4*)(claim + ((size_t)(b >> 2) * LCL + (b & 3) * 64) * DIM);
    float4 a = make_float4(0.f, 0.f, 0.f, 0.f);
#pragma unroll
    for (int r = 0; r < 16; ++r) {
        const float4 v = sp4[(rg * 16 + r) * 64 + d4];
        a.x += v.x; a.y += v.y; a.z += v.z; a.w += v.w;
    }
    red[rg][d4] = a;
    __syncthreads();
    if (t < 64) {
        float4 s = make_float4(0.f, 0.f, 0.f, 0.f);
#pragma unroll
        for (int j = 0; j < 4; ++j) {
            const float4 v = red[j][t];
            s.x += v.x; s.y += v.y; s.z += v.z; s.w += v.w;
        }
        ((float4*)(cpart + (size_t)b * DIM))[t] = s;
    }
}

// ---------------------------------------------------------------------------
// K2: bias[pair][o] = (sum_chunks src / count) @ W[D:2D]
// src: nchunks partial rows of 256 per pair; scale = 1/count.
// ---------------------------------------------------------------------------
__global__ __launch_bounds__(256) void k_bias(
    const float* __restrict__ src, int nchunks, float scale,
    const float* __restrict__ W, float* __restrict__ bias)
{
    const int pair = blockIdx.x;
    const int t = threadIdx.x;
    __shared__ float sm[DIM];
    __shared__ float sb[2][OUTD];
    float s = 0.f;
    for (int j = 0; j < nchunks; ++j)
        s += src[((size_t)pair * nchunks + j) * DIM + t];
    sm[t] = s * scale;
    __syncthreads();
    const int o = t & 127, dh = t >> 7;
    float b = 0.f;
#pragma unroll 8
    for (int i = 0; i < 128; ++i) {
        const int d = dh * 128 + i;
        b += sm[d] * W[(size_t)(DIM + d) * OUTD + o];
    }
    sb[dh][o] = b;
    __syncthreads();
    if (t < 128) bias[pair * OUTD + t] = sb[0][t] + sb[1][t];
}

// ---------------------------------------------------------------------------
// K3: fully fused per-pair attention: GEMM (MFMA bf16) -> tanh -> dot(w)
// -> masked softmax -> weighted sum. One block per pair, 512 thr = 8 waves.
// If MEAN: also emits raw column sums of seq (for the other side's bias).
// ---------------------------------------------------------------------------
template <int L, bool MEAN>
__global__ __launch_bounds__(512) void k_fused(
    const float* __restrict__ seq, const unsigned short* __restrict__ WT,
    const float* __restrict__ wvec, const float* __restrict__ bias,
    const int* __restrict__ mask, float* __restrict__ outp,
    float* __restrict__ meanout)
{
    constexpr int SAPC = 264;                    // 256 + 8 bf16 pad
    __shared__ unsigned short sA[128 * SAPC];    // 67584 B
    __shared__ float satt[L];
    __shared__ float sred8[8], ssum8[8];
    __shared__ float4 red2[8][64];               // 8 KB (mean reduce + wsum reduce)

    const int pair = blockIdx.x;
    const int t = threadIdx.x;
    const int lane = t & 63, w = t >> 6;
    const int q = lane >> 4, c16 = lane & 15;
    const int d4 = t & 63, lg = t >> 6;

    const float4* sp4 = (const float4*)(seq + (size_t)pair * L * DIM);

    float bc[8], wc[8];
#pragma unroll
    for (int ct = 0; ct < 8; ++ct) {
        bc[ct] = bias[pair * OUTD + ct * 16 + c16];
        wc[ct] = wvec[ct * 16 + c16];
    }

    float4 macc = make_float4(0.f, 0.f, 0.f, 0.f);

    for (int tile = 0; tile < L / 128; ++tile) {
        __syncthreads();                         // protect sA reuse
        // stage 128 rows x 256 k, fp32 -> bf16; f4-column fixed per thread
#pragma unroll
        for (int i = 0; i < 16; ++i) {
            const int row = (t + i * 512) >> 6;  // 0..127
            const float4 v = sp4[(tile * 128 + row) * 64 + d4];
            if (MEAN) { macc.x += v.x; macc.y += v.y; macc.z += v.z; macc.w += v.w; }
            BF2 lo, hi;
            lo.h = __float22bfloat162_rn(make_float2(v.x, v.y));
            hi.h = __float22bfloat162_rn(make_float2(v.z, v.w));
            *(uint2*)&sA[row * SAPC + d4 * 4] = make_uint2(lo.u, hi.u);
        }
        __syncthreads();

        floatx4 acc[8];
#pragma unroll
        for (int ct = 0; ct < 8; ++ct) acc[ct] = (floatx4){0.f, 0.f, 0.f, 0.f};
#pragma unroll
        for (int ks = 0; ks < 8; ++ks) {
            const bf16x8 af = *(const bf16x8*)&sA[(w * 16 + c16) * SAPC + ks * 32 + q * 8];
#pragma unroll
            for (int ct = 0; ct < 8; ++ct) {
                const bf16x8 bf = *(const bf16x8*)(WT + (size_t)(ct * 16 + c16) * DIM + ks * 32 + q * 8);
                acc[ct] = __builtin_amdgcn_mfma_f32_16x16x32_bf16(af, bf, acc[ct], 0, 0, 0);
            }
        }
        // epilogue: tanh + dot(w), reduce over 128 cols (16 lanes x 8 ct)
#pragma unroll
        for (int reg = 0; reg < 4; ++reg) {
            float s = 0.f;
#pragma unroll
            for (int ct = 0; ct < 8; ++ct)
                s += fast_tanh(acc[ct][reg] + bc[ct]) * wc[ct];
#pragma unroll
            for (int off = 1; off < 16; off <<= 1) s += __shfl_xor(s, off, 64);
            if (c16 == 0)
                satt[tile * 128 + w * 16 + q * 4 + reg] = s;
        }
    }
    __syncthreads();

    if (MEAN) {
        red2[lg][d4] = macc;
        __syncthreads();
        if (t < 64) {
            float4 s = make_float4(0.f, 0.f, 0.f, 0.f);
#pragma unroll
            for (int j = 0; j < 8; ++j) {
                const float4 v = red2[j][t];
                s.x += v.x; s.y += v.y; s.z += v.z; s.w += v.w;
            }
            ((float4*)(meanout + (size_t)pair * DIM))[t] = s;
        }
        __syncthreads();                          // before red2 reuse
    }

    // masked softmax over L (in LDS)
    float a = -INFINITY;
    if (t < L) a = mask[pair * L + t] ? satt[t] : NEGV;
    float lmax = a;
#pragma unroll
    for (int off = 32; off > 0; off >>= 1) lmax = fmaxf(lmax, __shfl_xor(lmax, off, 64));
    if (lane == 0) sred8[w] = lmax;
    __syncthreads();
    float gmax = -INFINITY;
#pragma unroll
    for (int j = 0; j < 8; ++j) gmax = fmaxf(gmax, sred8[j]);
    float e = 0.f;
    if (t < L) { e = __expf(a - gmax); satt[t] = e; }
    float lsum = e;
#pragma unroll
    for (int off = 32; off > 0; off >>= 1) lsum += __shfl_xor(lsum, off, 64);
    if (lane == 0) ssum8[w] = lsum;
    __syncthreads();

    // weighted sum: lg picks an L/8 row chunk, d4 a float4 column
    constexpr int LC = L / 8;
    float4 o = make_float4(0.f, 0.f, 0.f, 0.f);
    for (int l = lg * LC; l < (lg + 1) * LC; ++l) {
        const float pl = satt[l];
        const float4 v = sp4[l * 64 + d4];
        o.x += pl * v.x; o.y += pl * v.y; o.z += pl * v.z; o.w += pl * v.w;
    }
    red2[lg][d4] = o;
    __syncthreads();
    if (t < 64) {
        float4 s = make_float4(0.f, 0.f, 0.f, 0.f);
#pragma unroll
        for (int j = 0; j < 8; ++j) {
            const float4 v = red2[j][t];
            s.x += v.x; s.y += v.y; s.z += v.z; s.w += v.w;
        }
        const float gsum = ssum8[0] + ssum8[1] + ssum8[2] + ssum8[3]
                         + ssum8[4] + ssum8[5] + ssum8[6] + ssum8[7];
        const float inv = 1.f / gsum;
        ((float4*)(outp + (size_t)pair * DIM))[t] =
            make_float4(s.x * inv, s.y * inv, s.z * inv, s.w * inv);
    }
}

// ---------------------------------------------------------------------------
extern "C" void kernel_launch(void* const* d_in, const int* in_sizes, int n_in,
                              void* d_out, int out_size, void* d_ws, size_t ws_size,
                              hipStream_t stream) {
    const float* claim    = (const float*)d_in[0];
    const int*   cmask    = (const int*)  d_in[1];
    const float* evidence = (const float*)d_in[2];
    const int*   emask    = (const int*)  d_in[3];
    const float* W1       = (const float*)d_in[4];
    const float* w2       = (const float*)d_in[5];
    const float* W2       = (const float*)d_in[6];
    const float* w1       = (const float*)d_in[7];
    float* out = (float*)d_out;

    float* ws = (float*)d_ws;
    float* cpart  = ws;                          // 1024*256 = 262144 floats
    float* emean  = cpart + 1024 * DIM;          // 256*256
    float* bias_e = emean + BE * DIM;            // 256*128
    float* bias_c = bias_e + BE * OUTD;          // 256*128
    unsigned short* WT1 = (unsigned short*)(bias_c + BE * OUTD);
    unsigned short* WT2 = WT1 + OUTD * DIM;

    k_prep<<<1280, 256, 0, stream>>>(claim, W1, W2, cpart, WT1, WT2);
    k_bias<<<BE, 256, 0, stream>>>(cpart, 4, 1.f / LCL, W1, bias_e);
    // e_hat (second half of out); also emits evidence column sums
    k_fused<LEV, true><<<BE, 512, 0, stream>>>(evidence, WT1, w2, bias_e, emask,
                                               out + BE * DIM, emean);
    k_bias<<<BE, 256, 0, stream>>>(emean, 1, 1.f / LEV, W2, bias_c);
    // c_hat (first half of out)
    k_fused<LCL, false><<<BE, 512, 0, stream>>>(claim, WT2, w1, bias_c, cmask,
                                                out, nullptr);
}

// Round 5
// 353.873 us; speedup vs baseline: 1.3181x; 1.3181x over previous
//
#include <hip/hip_runtime.h>
#include <hip/hip_bf16.h>
#include <math.h>

#define BE   256
#define DIM  256
#define OUTD 128
#define LCL  256
#define LEV  512
#define NEGV -1e18f

typedef short  bf16x8  __attribute__((ext_vector_type(8)));
typedef float  floatx4 __attribute__((ext_vector_type(4)));

union BF1 { __hip_bfloat16 h; unsigned short u; };
union BF2 { __hip_bfloat162 h; unsigned int u; };

__device__ __forceinline__ float fast_tanh(float x) {
    float xc = fminf(fmaxf(x, -15.f), 15.f);
    float e = __expf(2.f * xc);
    return (e - 1.f) * __builtin_amdgcn_rcpf(e + 1.f);
}

// ---------------------------------------------------------------------------
// K1: float4 partial column-sums for claim AND evidence + W->bf16 transpose.
// blocks [0,1024): claim, pair=b>>2, chunk=b&3 (64 rows)
// blocks [1024,3072): evidence, idx=b-1024, pair=idx>>3, chunk=idx&7 (64 rows)
// blocks [3072,3328): WT transpose (fp32 W[:D] -> bf16 W^T 128x256)
// ---------------------------------------------------------------------------
__global__ __launch_bounds__(256) void k_prep(
    const float* __restrict__ claim, const float* __restrict__ evidence,
    const float* __restrict__ W1, const float* __restrict__ W2,
    float* __restrict__ cpart, float* __restrict__ epart,
    unsigned short* __restrict__ WT1, unsigned short* __restrict__ WT2)
{
    const int b = blockIdx.x;
    const int t = threadIdx.x;
    if (b >= 3072) {
        const int idx = b - 3072;
        const int side = idx >> 7;
        const int n = idx & 127;
        const float* W = side ? W2 : W1;
        unsigned short* WT = side ? WT2 : WT1;
        BF1 c; c.h = __float2bfloat16(W[(size_t)t * OUTD + n]);
        WT[n * DIM + t] = c.u;
        return;
    }
    __shared__ float4 red[4][64];
    const int d4 = t & 63, rg = t >> 6;
    const float4* sp4;
    float* dst;
    if (b < 1024) {
        sp4 = (const float4*)(claim + ((size_t)(b >> 2) * LCL + (b & 3) * 64) * DIM);
        dst = cpart + (size_t)b * DIM;
    } else {
        const int idx = b - 1024;
        sp4 = (const float4*)(evidence + ((size_t)(idx >> 3) * LEV + (idx & 7) * 64) * DIM);
        dst = epart + (size_t)idx * DIM;
    }
    float4 a = make_float4(0.f, 0.f, 0.f, 0.f);
#pragma unroll
    for (int r = 0; r < 16; ++r) {
        const float4 v = sp4[(rg * 16 + r) * 64 + d4];
        a.x += v.x; a.y += v.y; a.z += v.z; a.w += v.w;
    }
    red[rg][d4] = a;
    __syncthreads();
    if (t < 64) {
        float4 s = make_float4(0.f, 0.f, 0.f, 0.f);
#pragma unroll
        for (int j = 0; j < 4; ++j) {
            const float4 v = red[j][t];
            s.x += v.x; s.y += v.y; s.z += v.z; s.w += v.w;
        }
        ((float4*)dst)[t] = s;
    }
}

// ---------------------------------------------------------------------------
// K2: both bias GEMMs in one launch. grid (BE, 2).
// y=0: bias_e = (claim mean) @ W1[D:];  y=1: bias_c = (evid mean) @ W2[D:]
// ---------------------------------------------------------------------------
__global__ __launch_bounds__(256) void k_bias(
    const float* __restrict__ cpart, const float* __restrict__ epart,
    const float* __restrict__ W1, const float* __restrict__ W2,
    float* __restrict__ bias_e, float* __restrict__ bias_c)
{
    const int pair = blockIdx.x;
    const int side = blockIdx.y;
    const int t = threadIdx.x;
    const float* src = side ? epart : cpart;
    const int nch = side ? 8 : 4;
    const float scale = side ? (1.f / LEV) : (1.f / LCL);
    const float* W = side ? W2 : W1;
    float* bias = side ? bias_c : bias_e;

    __shared__ float sm[DIM];
    __shared__ float sb[2][OUTD];
    float s = 0.f;
    for (int j = 0; j < nch; ++j)
        s += src[((size_t)pair * nch + j) * DIM + t];
    sm[t] = s * scale;
    __syncthreads();
    const int o = t & 127, dh = t >> 7;
    float b = 0.f;
#pragma unroll 8
    for (int i = 0; i < 128; ++i) {
        const int d = dh * 128 + i;
        b += sm[d] * W[(size_t)(DIM + d) * OUTD + o];
    }
    sb[dh][o] = b;
    __syncthreads();
    if (t < 128) bias[pair * OUTD + t] = sb[0][t] + sb[1][t];
}

// ---------------------------------------------------------------------------
// K3: MFMA attention-score body (identical structure to R2's proven k_att:
// 256 thr, 128-row tile, 34 KB LDS -> 4 blocks/CU, 0 bank conflicts).
// ---------------------------------------------------------------------------
template <int L>
__device__ __forceinline__ void att_body(
    const float* __restrict__ seq, const unsigned short* __restrict__ WT,
    const float* __restrict__ wvec, const float* __restrict__ bias,
    float* __restrict__ att, int pair, int tile,
    unsigned short* __restrict__ sA, float (*__restrict__ sred)[2])
{
    constexpr int SAPC = 136;                 // padded k-stride (128+8) bf16
    const int t = threadIdx.x;
    const int lane = t & 63;
    const int wv = t >> 6;
    const int wrow = wv >> 1, wcolg = wv & 1;
    const int q = lane >> 4, c16 = lane & 15;
    const int rowbase = tile * 128;

    const float4* sp4 = (const float4*)(seq + ((size_t)pair * L + rowbase) * DIM);

    floatx4 acc[4][4];
#pragma unroll
    for (int ra = 0; ra < 4; ++ra)
#pragma unroll
        for (int ct = 0; ct < 4; ++ct) acc[ra][ct] = (floatx4){0.f, 0.f, 0.f, 0.f};

    const unsigned short* wbase = WT + (size_t)(wcolg * 64 + c16) * DIM + q * 8;
    bf16x8 bcur[4], bnxt[4];
#pragma unroll
    for (int ct = 0; ct < 4; ++ct)
        bcur[ct] = *(const bf16x8*)(wbase + ct * 16 * DIM);

    for (int kc = 0; kc < 2; ++kc) {
        __syncthreads();
#pragma unroll
        for (int i = 0; i < 16; ++i) {
            const int idx = t + i * 256;
            const int row = idx >> 5;
            const int f4 = idx & 31;
            const float4 v = sp4[row * 64 + kc * 32 + f4];
            BF2 lo, hi;
            lo.h = __float22bfloat162_rn(make_float2(v.x, v.y));
            hi.h = __float22bfloat162_rn(make_float2(v.z, v.w));
            *(uint2*)&sA[row * SAPC + f4 * 4] = make_uint2(lo.u, hi.u);
        }
        __syncthreads();
#pragma unroll
        for (int ks4 = 0; ks4 < 4; ++ks4) {
            const int ks = kc * 4 + ks4;
            if (ks < 7) {
#pragma unroll
                for (int ct = 0; ct < 4; ++ct)
                    bnxt[ct] = *(const bf16x8*)(wbase + ct * 16 * DIM + (ks + 1) * 32);
            }
            bf16x8 af[4];
#pragma unroll
            for (int ra = 0; ra < 4; ++ra)
                af[ra] = *(const bf16x8*)&sA[(wrow * 64 + ra * 16 + c16) * SAPC + ks4 * 32 + q * 8];
#pragma unroll
            for (int ra = 0; ra < 4; ++ra)
#pragma unroll
                for (int ct = 0; ct < 4; ++ct)
                    acc[ra][ct] = __builtin_amdgcn_mfma_f32_16x16x32_bf16(af[ra], bcur[ct], acc[ra][ct], 0, 0, 0);
#pragma unroll
            for (int ct = 0; ct < 4; ++ct) bcur[ct] = bnxt[ct];
        }
    }

    float bc[4], wc[4];
#pragma unroll
    for (int ct = 0; ct < 4; ++ct) {
        const int col = wcolg * 64 + ct * 16 + c16;
        bc[ct] = bias[pair * OUTD + col];
        wc[ct] = wvec[col];
    }
#pragma unroll
    for (int ra = 0; ra < 4; ++ra) {
#pragma unroll
        for (int reg = 0; reg < 4; ++reg) {
            float s = 0.f;
#pragma unroll
            for (int ct = 0; ct < 4; ++ct)
                s += fast_tanh(acc[ra][ct][reg] + bc[ct]) * wc[ct];
#pragma unroll
            for (int off = 1; off < 16; off <<= 1) s += __shfl_xor(s, off, 64);
            if (c16 == 0)
                sred[wrow * 64 + ra * 16 + q * 4 + reg][wcolg] = s;
        }
    }
    __syncthreads();
    if (t < 128)
        att[(size_t)pair * L + rowbase + t] = sred[t][0] + sred[t][1];
}

// grid (BE, 6): y<4 evidence tile y; y>=4 claim tile y-4
__global__ __launch_bounds__(256) void k_att(
    const float* __restrict__ claim, const float* __restrict__ evidence,
    const unsigned short* __restrict__ WT1, const unsigned short* __restrict__ WT2,
    const float* __restrict__ w2v, const float* __restrict__ w1v,
    const float* __restrict__ bias_e, const float* __restrict__ bias_c,
    float* __restrict__ att_e, float* __restrict__ att_c)
{
    __shared__ unsigned short sA[128 * 136];
    __shared__ float sred[128][2];
    if (blockIdx.y < 4)
        att_body<LEV>(evidence, WT1, w2v, bias_e, att_e, blockIdx.x, blockIdx.y, sA, sred);
    else
        att_body<LCL>(claim, WT2, w1v, bias_c, att_c, blockIdx.x, blockIdx.y - 4, sA, sred);
}

// ---------------------------------------------------------------------------
// K4: masked softmax + weighted sum body (R2 structure, wsum unrolled x4).
// ---------------------------------------------------------------------------
template <int L>
__device__ __forceinline__ void soft_body(
    const float* __restrict__ seq, const int* __restrict__ mask,
    const float* __restrict__ att, float* __restrict__ outp, int pair,
    float* __restrict__ p, float* __restrict__ red, float4 (*__restrict__ red2)[64])
{
    const int t = threadIdx.x;

    if (t < 256) {
        float lmax = -INFINITY;
#pragma unroll
        for (int k = 0; k < L / 256; ++k) {
            const int i = t + k * 256;
            float a = att[(size_t)pair * L + i];
            a = mask[pair * L + i] ? a : NEGV;
            p[i] = a;
            lmax = fmaxf(lmax, a);
        }
#pragma unroll
        for (int off = 32; off > 0; off >>= 1) lmax = fmaxf(lmax, __shfl_xor(lmax, off, 64));
        if ((t & 63) == 0) red[t >> 6] = lmax;
    }
    __syncthreads();
    if (t < 256) {
        const float gmax = fmaxf(fmaxf(red[0], red[1]), fmaxf(red[2], red[3]));
        float lsum = 0.f;
#pragma unroll
        for (int k = 0; k < L / 256; ++k) {
            const int i = t + k * 256;
            const float e = __expf(p[i] - gmax);
            p[i] = e;
            lsum += e;
        }
#pragma unroll
        for (int off = 32; off > 0; off >>= 1) lsum += __shfl_xor(lsum, off, 64);
        if ((t & 63) == 0) red[4 + (t >> 6)] = lsum;
    }
    __syncthreads();

    const int d4 = t & 63, lg = t >> 6;
    constexpr int LC = L / 16;
    const float4* sp4 = (const float4*)(seq + (size_t)pair * L * DIM);
    float4 o = make_float4(0.f, 0.f, 0.f, 0.f);
#pragma unroll 4
    for (int l = lg * LC; l < (lg + 1) * LC; ++l) {
        const float pl = p[l];
        const float4 v = sp4[l * 64 + d4];
        o.x += pl * v.x; o.y += pl * v.y; o.z += pl * v.z; o.w += pl * v.w;
    }
    red2[lg][d4] = o;
    __syncthreads();
    if (t < 64) {
        float4 s = make_float4(0.f, 0.f, 0.f, 0.f);
#pragma unroll
        for (int j = 0; j < 16; ++j) {
            const float4 v = red2[j][t];
            s.x += v.x; s.y += v.y; s.z += v.z; s.w += v.w;
        }
        const float inv = 1.f / (red[4] + red[5] + red[6] + red[7]);
        ((float4*)(outp + (size_t)pair * DIM))[t] =
            make_float4(s.x * inv, s.y * inv, s.z * inv, s.w * inv);
    }
}

// grid 512: b<256 claim -> out[0..], b>=256 evidence -> out[BE*DIM..]
__global__ __launch_bounds__(1024) void k_soft(
    const float* __restrict__ claim, const float* __restrict__ evidence,
    const int* __restrict__ cmask, const int* __restrict__ emask,
    const float* __restrict__ att_e, const float* __restrict__ att_c,
    float* __restrict__ out)
{
    __shared__ float p[LEV];
    __shared__ float red[8];
    __shared__ float4 red2[16][64];
    if (blockIdx.x < BE)
        soft_body<LCL>(claim, cmask, att_c, out, blockIdx.x, p, red, red2);
    else
        soft_body<LEV>(evidence, emask, att_e, out + BE * DIM, blockIdx.x - BE, p, red, red2);
}

// ---------------------------------------------------------------------------
extern "C" void kernel_launch(void* const* d_in, const int* in_sizes, int n_in,
                              void* d_out, int out_size, void* d_ws, size_t ws_size,
                              hipStream_t stream) {
    const float* claim    = (const float*)d_in[0];
    const int*   cmask    = (const int*)  d_in[1];
    const float* evidence = (const float*)d_in[2];
    const int*   emask    = (const int*)  d_in[3];
    const float* W1       = (const float*)d_in[4];
    const float* w2       = (const float*)d_in[5];
    const float* W2       = (const float*)d_in[6];
    const float* w1       = (const float*)d_in[7];
    float* out = (float*)d_out;

    float* ws = (float*)d_ws;
    float* cpart  = ws;                          // 1024*256
    float* epart  = cpart + 1024 * DIM;          // 2048*256
    float* bias_e = epart + 2048 * DIM;          // 256*128
    float* bias_c = bias_e + BE * OUTD;          // 256*128
    float* att_e  = bias_c + BE * OUTD;          // 256*512
    float* att_c  = att_e + BE * LEV;            // 256*256
    unsigned short* WT1 = (unsigned short*)(att_c + BE * LCL);
    unsigned short* WT2 = WT1 + OUTD * DIM;

    k_prep<<<3328, 256, 0, stream>>>(claim, evidence, W1, W2, cpart, epart, WT1, WT2);
    k_bias<<<dim3(BE, 2), 256, 0, stream>>>(cpart, epart, W1, W2, bias_e, bias_c);
    k_att<<<dim3(BE, 6), 256, 0, stream>>>(claim, evidence, WT1, WT2, w2, w1,
                                           bias_e, bias_c, att_e, att_c);
    k_soft<<<512, 1024, 0, stream>>>(claim, evidence, cmask, emask, att_e, att_c, out);
}